// Round 11
// baseline (133.241 us; speedup 1.0000x reference)
//
#include <hip/hip_runtime.h>
#include <stdint.h>

// VQ-VAE vector quantizer, MI355X — pack + fused(argmin+gather) pipeline.
// z: (32, 256, 32, 32) fp32 ; embedding: (1024, 256) fp32
// out: [0, 8388608) quant_z (N,C,H,W) ; [8388608] vq_loss ; [8388609] commit_loss
//
//   argmin_k ||z-e_k||^2 = argmin_k ( ||e_k||^2 - 2 z.e_k )   [bf16 MFMA scores]
//   vq_loss = (sum_m (||z_m||^2 + s_min(m))) / (M*C), commit = 0.25*vq_loss
//
// Round-11: r10's argmin (barrier-free per-wave counted-vmcnt pipeline, af from
// zb16) fused with r5's proven 64-row gather epilogue (gtile aliases the dead
// chunk buffers) and r1's completion-counter loss finalize. Rationale: in the
// 3-dispatch chain, gather cannot start until the LAST argmin block retires, so
// its ~10 us is fully exposed; as a per-block epilogue it overlaps other blocks'
// MFMA loops. Indices stay in LDS (WS_IDX round-trip deleted); one dispatch gap
// deleted. vq_pack unchanged from r10.

#define CDIM  256

// ws byte offsets
#define WS_ZB16   0u           // bf16 z-fragments, unit16B = (rb*8+kg)*64+lk*16+lrow (16 MB)
#define WS_EB     16777216u    // bf16[1024][256] row-major (512 KB)
#define WS_ENORM  17301504u    // f32[1024]
#define WS_ZNORM  17305600u    // f32[32768]
#define WS_CNT    17436672u    // u32 completion counter
#define WS_LOSS   19664896u    // f32

// fused-kernel LDS (dynamic, 71936 B)
#define L_BUFS   0u            // 4 waves x 2 x 8 KB chunk double-buffers
#define L_ENORM  65536u        // f32[1024], wave w owns [w*256, w*256+256)
#define L_CAND   69632u        // float2[4][64]
#define L_IDX    71680u        // i32[64]
#define LDS_TOTAL 71936
#define GT_STRIDE 67           // gather tile f32[128 c][67] aliases bufs (34304 B)

typedef __attribute__((ext_vector_type(8))) short bf16x8;
typedef __attribute__((ext_vector_type(4))) float f32x4;

__device__ inline unsigned short f2bf(float f) {
  uint32_t u = __float_as_uint(f);
  return (unsigned short)((u + 0x7FFFu + ((u >> 16) & 1u)) >> 16);
}

__device__ inline void load16(const void* g, void* l) {
  __builtin_amdgcn_global_load_lds((const __attribute__((address_space(1))) void*)g,
                                   (__attribute__((address_space(3))) void*)l, 16, 0, 0);
}

// blocks 0..511: z (c-major f32) -> zb16 (bf16 MFMA-fragment layout) + znorm.
// blocks 512..767: E -> bf16 Eb (row-major) + eNorm ; block 512 zeroes loss+cnt.
__global__ __launch_bounds__(256)
void vq_pack(const float* __restrict__ z, const float* __restrict__ E,
             char* __restrict__ ws) {
  __shared__ float tileF[32 * 66];
  __shared__ float znPart[256];
  const int t = threadIdx.x;
  const int mt = blockIdx.x;

  if (mt >= 512) {                           // ---- prep_e part ----
    const int bb = mt - 512;                 // 0..255
    const int w = t >> 6, l = t & 63;
    const int row = bb * 4 + w;
    const float4 v = *(const float4*)(E + (size_t)row * CDIM + l * 4);
    ushort4 b;
    b.x = f2bf(v.x); b.y = f2bf(v.y); b.z = f2bf(v.z); b.w = f2bf(v.w);
    *(ushort4*)(ws + WS_EB + (size_t)row * 512 + l * 8) = b;
    float s = v.x * v.x + v.y * v.y + v.z * v.z + v.w * v.w;
    #pragma unroll
    for (int m = 32; m >= 1; m >>= 1) s += __shfl_xor(s, m);
    if (l == 0) ((float*)(ws + WS_ENORM))[row] = s;
    if (bb == 0 && t == 0) {
      *((float*)(ws + WS_LOSS)) = 0.f;
      *((unsigned*)(ws + WS_CNT)) = 0u;
    }
    return;
  }

  // ---- pack_z part (proven round-6/7/10) ----
  const int n = mt >> 4, hw0 = (mt & 15) << 6;
  const int m0 = mt << 6;
  const float* zb0 = z + (size_t)n * (CDIM * 1024) + hw0;
  const int cA = (t >> 4) * 2, hA = (t & 15) * 4;   // loader: 2 c-rows x 4 hw
  const int r = t >> 2, lk = t & 3;                 // packer: row r, c-subgroup lk
  const int rb = (m0 + r) >> 4, lrow = r & 15;
  char* zb16 = ws + WS_ZB16;

  float4 v0 = *(const float4*)(zb0 + (size_t)cA * 1024 + hA);
  float4 v1 = *(const float4*)(zb0 + (size_t)(cA + 1) * 1024 + hA);
  float znAcc = 0.f;
  for (int ci = 0; ci < 8; ++ci) {           // chunk ci == MFMA k-group kg
    __syncthreads();                         // tileF free
    *(float4*)(tileF + cA * 66 + hA)       = v0;
    *(float4*)(tileF + (cA + 1) * 66 + hA) = v1;
    if (ci < 7) {
      const float* src = zb0 + (size_t)((ci + 1) * 32 + cA) * 1024 + hA;
      v0 = *(const float4*)(src);
      v1 = *(const float4*)(src + 1024);
    }
    __syncthreads();                         // tileF ready
    union { bf16x8 v; unsigned short u[8]; } pk;
    #pragma unroll
    for (int k = 0; k < 8; ++k) {            // c = ci*32 + lk*8 + k
      const float sv = tileF[(lk * 8 + k) * 66 + r];
      znAcc += sv * sv;
      pk.u[k] = f2bf(sv);
    }
    *(bf16x8*)(zb16 + ((size_t)((rb * 8 + ci) * 64 + lk * 16 + lrow)) * 16) = pk.v;
  }
  znPart[t] = znAcc;                         // (r,lk) -> r*4+lk == t
  __syncthreads();
  if (t < 64)
    ((float*)(ws + WS_ZNORM))[m0 + t] =
        znPart[t * 4] + znPart[t * 4 + 1] + znPart[t * 4 + 2] + znPart[t * 4 + 3];
}

// Fused argmin + gather + finalize: 512 blocks x 256 thr (4 independent waves).
// Wave w owns codes [w*256, w*256+256) in 16 chunks of 16; private 2x8KB LDS
// double buffer; main loop has no s_barrier — per-wave counted vmcnt only.
// Epilogue: gather quant_z via gtile (aliases dead bufs) + counter finalize.
__global__ __launch_bounds__(256)
__attribute__((amdgpu_waves_per_eu(2, 2)))
void vq_argmin_gather(const float* __restrict__ E, char* __restrict__ ws,
                      float* __restrict__ out) {
  extern __shared__ char lds[];
  const int t = threadIdx.x, w = t >> 6, l = t & 63;
  const int lrow = l & 15, lk = l >> 4;
  const int mt = blockIdx.x;                 // 0..511
  const int m0 = mt << 6;
  const int n = mt >> 4, hw0 = (mt & 15) << 6;
  const char* Eb   = ws + WS_EB;
  const char* zb16 = ws + WS_ZB16;

  char* bufA    = lds + L_BUFS + w * 16384;  // wave-private chunk buffers
  char* bufB    = bufA + 8192;
  float* eNormW = (float*)(lds + L_ENORM + w * 1024);  // wave's 256 norms
  float2* cand  = (float2*)(lds + L_CAND);   // [4 waves][64 rows]
  int* idxS     = (int*)(lds + L_IDX);       // i32[64]
  float* gtile  = (float*)(lds);             // epilogue, aliases chunk bufs (dead)

  // staging source offsets for one 16-code chunk (XOR granule swizzle baked in):
  // LDS[q][s] = E[q][s ^ (q&7)], q = code-in-chunk, s/granule of 16 B.
  int srcOff[8];
  #pragma unroll
  for (int i = 0; i < 8; ++i) {
    const int j = i * 64 + l;                // LDS granule 0..511
    const int q = j >> 5;                    // code-in-chunk 0..15
    const int g = (j & 31) ^ (q & 7);        // source granule (un-swizzle)
    srcOff[i] = q * 512 + g * 16;
  }
  const char* EbW = Eb + (size_t)w * 131072; // wave's 256 codes (128 KB)

  // stage chunk 0 + wave's eNorm slice (9 loads outstanding)
  #pragma unroll
  for (int i = 0; i < 8; ++i)
    load16(EbW + srcOff[i], bufA + i * 1024 + l * 16);
  load16((const char*)(ws + WS_ENORM) + w * 1024 + l * 16, (char*)eNormW + l * 16);

  // af: 64 rows x K=256, identical in all waves (proven round-6 layout)
  bf16x8 af[4][8];
  const int rb0 = mt * 4;
  #pragma unroll
  for (int rs = 0; rs < 4; ++rs)
    #pragma unroll
    for (int kg = 0; kg < 8; ++kg)
      af[rs][kg] = *(const bf16x8*)(zb16 + ((size_t)(((rb0 + rs) * 8 + kg) * 64 + l)) * 16);

  float bb[4][4]; int bidx[4][4];
  #pragma unroll
  for (int rs = 0; rs < 4; ++rs)
    #pragma unroll
    for (int i = 0; i < 4; ++i) { bb[rs][i] = 3.4e38f; bidx[rs][i] = 0; }

  char* bcur = bufA;
  char* bnxt = bufB;
  for (int ch = 0; ch < 16; ++ch) {
    if (ch < 15) {                           // stage next chunk into other buf
      const char* src = EbW + (size_t)(ch + 1) * 8192;
      #pragma unroll
      for (int i = 0; i < 8; ++i)
        load16(src + srcOff[i], bnxt + i * 1024 + l * 16);
      // retire everything except the 8 loads just issued (chunk ch ready)
      asm volatile("s_waitcnt vmcnt(8)" ::: "memory");
    } else {
      asm volatile("s_waitcnt vmcnt(0)" ::: "memory");
    }
    __builtin_amdgcn_sched_barrier(0);

    f32x4 acc[4];
    #pragma unroll
    for (int rs = 0; rs < 4; ++rs) acc[rs] = (f32x4){0.f, 0.f, 0.f, 0.f};
    const char* ebase = bcur + lrow * 512;
    #pragma unroll
    for (int kg = 0; kg < 8; ++kg) {
      const bf16x8 bf = *(const bf16x8*)(ebase + (((kg * 4 + lk) ^ (lrow & 7)) * 16));
      acc[0] = __builtin_amdgcn_mfma_f32_16x16x32_bf16(af[0][kg], bf, acc[0], 0, 0, 0);
      acc[1] = __builtin_amdgcn_mfma_f32_16x16x32_bf16(af[1][kg], bf, acc[1], 0, 0, 0);
      acc[2] = __builtin_amdgcn_mfma_f32_16x16x32_bf16(af[2][kg], bf, acc[2], 0, 0, 0);
      acc[3] = __builtin_amdgcn_mfma_f32_16x16x32_bf16(af[3][kg], bf, acc[3], 0, 0, 0);
    }
    // fold (codes ascending within wave; strict < keeps first index)
    const int code = w * 256 + ch * 16 + lrow;
    const float eN = eNormW[ch * 16 + lrow];
    #pragma unroll
    for (int rs = 0; rs < 4; ++rs)
      #pragma unroll
      for (int i = 0; i < 4; ++i) {
        const float sc = fmaf(-2.f, acc[rs][i], eN);
        if (sc < bb[rs][i]) { bb[rs][i] = sc; bidx[rs][i] = code; }
      }
    char* tsw = bcur; bcur = bnxt; bnxt = tsw;
  }

  // reduce over 16 code-lanes (lrow bits), then cross-wave via LDS
  #pragma unroll
  for (int rs = 0; rs < 4; ++rs)
    #pragma unroll
    for (int i = 0; i < 4; ++i)
      #pragma unroll
      for (int m = 8; m >= 1; m >>= 1) {
        const float ob = __shfl_xor(bb[rs][i], m);
        const int   oi = __shfl_xor(bidx[rs][i], m);
        if (ob < bb[rs][i] || (ob == bb[rs][i] && oi < bidx[rs][i])) { bb[rs][i] = ob; bidx[rs][i] = oi; }
      }
  if (lrow == 0) {
    #pragma unroll
    for (int rs = 0; rs < 4; ++rs)
      #pragma unroll
      for (int i = 0; i < 4; ++i) {
        float2 c2; c2.x = bb[rs][i]; c2.y = __int_as_float(bidx[rs][i]);
        cand[w * 64 + rs * 16 + lk * 4 + i] = c2;   // row = rs*16+lk*4+i
      }
  }
  __syncthreads();                           // cand ready; all bufs consumed
  if (t < 64) {
    float best = 3.4e38f; int bi = 0x7fffffff;
    #pragma unroll
    for (int wv = 0; wv < 4; ++wv) {
      const float2 c2 = cand[wv * 64 + t];
      const int ci2 = __float_as_int(c2.y);
      if (c2.x < best || (c2.x == best && ci2 < bi)) { best = c2.x; bi = ci2; }
    }
    idxS[t] = bi;
    float d = ((const float*)(ws + WS_ZNORM))[m0 + t] + best;
    #pragma unroll
    for (int m = 32; m >= 1; m >>= 1) d += __shfl_xor(d, m);
    if (t == 0) atomicAdd((float*)(ws + WS_LOSS), d);
  }
  __syncthreads();                           // idxS ready; chunk bufs dead

  // ---- fused gather: quant_z = E[idx] (f32 exact), 2 c-passes of 128 ----
  // (r5-proven epilogue: gtile f32[128 c][67] aliases the dead chunk buffers)
  const int rIdx = t >> 2, qg = t & 3;
  const int gidx = idxS[rIdx];
  const float* erow = E + (size_t)gidx * CDIM;
  float* obase = out + (size_t)n * (CDIM * 1024) + hw0;
  const int ci2 = t >> 4, hwq = t & 15;
  #pragma unroll
  for (int p = 0; p < 2; ++p) {
    #pragma unroll
    for (int j = 0; j < 8; ++j) {
      const int cc = qg + j * 4;             // 0..31
      const float4 v = *(const float4*)(erow + p * 128 + cc * 4);
      gtile[(cc * 4 + 0) * GT_STRIDE + rIdx] = v.x;
      gtile[(cc * 4 + 1) * GT_STRIDE + rIdx] = v.y;
      gtile[(cc * 4 + 2) * GT_STRIDE + rIdx] = v.z;
      gtile[(cc * 4 + 3) * GT_STRIDE + rIdx] = v.w;
    }
    __syncthreads();
    #pragma unroll
    for (int j = 0; j < 8; ++j) {
      const int cl = ci2 + j * 16;           // 0..127
      float4 v;
      v.x = gtile[cl * GT_STRIDE + hwq * 4 + 0];
      v.y = gtile[cl * GT_STRIDE + hwq * 4 + 1];
      v.z = gtile[cl * GT_STRIDE + hwq * 4 + 2];
      v.w = gtile[cl * GT_STRIDE + hwq * 4 + 3];
      *(float4*)(obase + (size_t)(p * 128 + cl) * 1024 + hwq * 4) = v;
    }
    if (p == 0) __syncthreads();             // gtile reads done before pass-1 writes
  }

  // ---- last-block loss finalize (r1-proven) ----
  if (t == 0) {
    __threadfence();
    const unsigned done = atomicAdd((unsigned*)(ws + WS_CNT), 1u);
    if (done == 511u) {
      const float L = atomicAdd((float*)(ws + WS_LOSS), 0.0f) * (1.0f / 8388608.0f);
      out[8388608] = L;
      out[8388609] = 0.25f * L;
    }
  }
}

extern "C" void kernel_launch(void* const* d_in, const int* in_sizes, int n_in,
                              void* d_out, int out_size, void* d_ws, size_t ws_size,
                              hipStream_t stream) {
  const float* z = (const float*)d_in[0];
  const float* E = (const float*)d_in[1];
  float* out = (float*)d_out;
  char*  ws  = (char*)d_ws;

  static const int kLds = LDS_TOTAL;
  (void)hipFuncSetAttribute((const void*)vq_argmin_gather,
                            hipFuncAttributeMaxDynamicSharedMemorySize, kLds);

  vq_pack         <<<768, 256, 0, stream>>>(z, E, ws);
  vq_argmin_gather<<<512, 256, kLds, stream>>>(E, ws, out);
}

// Round 13
// 121.273 us; speedup vs baseline: 1.0987x; 1.0987x over previous
//
#include <hip/hip_runtime.h>
#include <stdint.h>

// VQ-VAE vector quantizer, MI355X — r10 pipeline + forced af register residency.
// z: (32, 256, 32, 32) fp32 ; embedding: (1024, 256) fp32
// out: [0, 8388608) quant_z (N,C,H,W) ; [8388608] vq_loss ; [8388609] commit_loss
//
//   argmin_k ||z-e_k||^2 = argmin_k ( ||e_k||^2 - 2 z.e_k )   [bf16 MFMA scores]
//   vq_loss = (sum_m (||z_m||^2 + s_min(m))) / (M*C), commit = 0.25*vq_loss
//
// Round-13 (= round-12 resubmit after infra failure): identical to round-10
// (best measured, 121.85) except vq_argmin pins af[4][8] in VGPRs with an asm
// keep-alive. Diagnosis (r11 counters): VGPR=112 < 128 needed for af alone, yet
// no scratch traffic => the compiler REMATERIALIZES af by re-loading it from
// zb16 (global) inside every chunk iteration — 32 dependent L2 loads
// interleaved with each chunk's MFMAs. The asm makes af opaque, forcing
// residency (budget 256 via waves_per_eu(2,2); ~220 VGPR still = 2 waves/EU).
// Keep-alive is expressed on 32-bit words (defensive vs 128-bit constraints).

#define CDIM  256

// ws byte offsets
#define WS_ZB16   0u           // bf16 z-fragments, unit16B = (rb*8+kg)*64+lk*16+lrow (16 MB)
#define WS_EB     16777216u    // bf16[1024][256] row-major (512 KB)
#define WS_ENORM  17301504u    // f32[1024]
#define WS_ZNORM  17305600u    // f32[32768]
#define WS_IDX    17436672u    // i32[32768]
#define WS_LOSS   19664896u    // f32

typedef __attribute__((ext_vector_type(8))) short bf16x8;
typedef __attribute__((ext_vector_type(4))) float f32x4;

__device__ inline unsigned short f2bf(float f) {
  uint32_t u = __float_as_uint(f);
  return (unsigned short)((u + 0x7FFFu + ((u >> 16) & 1u)) >> 16);
}

__device__ inline void load16(const void* g, void* l) {
  __builtin_amdgcn_global_load_lds((const __attribute__((address_space(1))) void*)g,
                                   (__attribute__((address_space(3))) void*)l, 16, 0, 0);
}

// blocks 0..511: z (c-major f32) -> zb16 (bf16 MFMA-fragment layout) + znorm.
// blocks 512..767: E -> bf16 Eb (row-major) + eNorm ; block 512 zeroes loss.
__global__ __launch_bounds__(256)
void vq_pack(const float* __restrict__ z, const float* __restrict__ E,
             char* __restrict__ ws) {
  __shared__ float tileF[32 * 66];
  __shared__ float znPart[256];
  const int t = threadIdx.x;
  const int mt = blockIdx.x;

  if (mt >= 512) {                           // ---- prep_e part ----
    const int bb = mt - 512;                 // 0..255
    const int w = t >> 6, l = t & 63;
    const int row = bb * 4 + w;
    const float4 v = *(const float4*)(E + (size_t)row * CDIM + l * 4);
    ushort4 b;
    b.x = f2bf(v.x); b.y = f2bf(v.y); b.z = f2bf(v.z); b.w = f2bf(v.w);
    *(ushort4*)(ws + WS_EB + (size_t)row * 512 + l * 8) = b;
    float s = v.x * v.x + v.y * v.y + v.z * v.z + v.w * v.w;
    #pragma unroll
    for (int m = 32; m >= 1; m >>= 1) s += __shfl_xor(s, m);
    if (l == 0) ((float*)(ws + WS_ENORM))[row] = s;
    if (bb == 0 && t == 0) *((float*)(ws + WS_LOSS)) = 0.f;
    return;
  }

  // ---- pack_z part (proven round-6/7/10) ----
  const int n = mt >> 4, hw0 = (mt & 15) << 6;
  const int m0 = mt << 6;
  const float* zb0 = z + (size_t)n * (CDIM * 1024) + hw0;
  const int cA = (t >> 4) * 2, hA = (t & 15) * 4;   // loader: 2 c-rows x 4 hw
  const int r = t >> 2, lk = t & 3;                 // packer: row r, c-subgroup lk
  const int rb = (m0 + r) >> 4, lrow = r & 15;
  char* zb16 = ws + WS_ZB16;

  float4 v0 = *(const float4*)(zb0 + (size_t)cA * 1024 + hA);
  float4 v1 = *(const float4*)(zb0 + (size_t)(cA + 1) * 1024 + hA);
  float znAcc = 0.f;
  for (int ci = 0; ci < 8; ++ci) {           // chunk ci == MFMA k-group kg
    __syncthreads();                         // tileF free
    *(float4*)(tileF + cA * 66 + hA)       = v0;
    *(float4*)(tileF + (cA + 1) * 66 + hA) = v1;
    if (ci < 7) {
      const float* src = zb0 + (size_t)((ci + 1) * 32 + cA) * 1024 + hA;
      v0 = *(const float4*)(src);
      v1 = *(const float4*)(src + 1024);
    }
    __syncthreads();                         // tileF ready
    union { bf16x8 v; unsigned short u[8]; } pk;
    #pragma unroll
    for (int k = 0; k < 8; ++k) {            // c = ci*32 + lk*8 + k
      const float sv = tileF[(lk * 8 + k) * 66 + r];
      znAcc += sv * sv;
      pk.u[k] = f2bf(sv);
    }
    *(bf16x8*)(zb16 + ((size_t)((rb * 8 + ci) * 64 + lk * 16 + lrow)) * 16) = pk.v;
  }
  znPart[t] = znAcc;                         // (r,lk) -> r*4+lk == t
  __syncthreads();
  if (t < 64)
    ((float*)(ws + WS_ZNORM))[m0 + t] =
        znPart[t * 4] + znPart[t * 4 + 1] + znPart[t * 4 + 2] + znPart[t * 4 + 3];
}

// Argmin: 512 blocks x 256 thr (4 independent waves). Wave w owns codes
// [w*256, w*256+256) in 16 chunks of 16; private 2x8KB LDS double buffer;
// main loop has no s_barrier — per-wave counted vmcnt only. af pinned resident.
__global__ __launch_bounds__(256)
__attribute__((amdgpu_waves_per_eu(2, 2)))
void vq_argmin(char* __restrict__ ws) {
  extern __shared__ char lds[];
  const int t = threadIdx.x, w = t >> 6, l = t & 63;
  const int lrow = l & 15, lk = l >> 4;
  const int mt = blockIdx.x;                 // 0..511
  const int m0 = mt << 6;
  const char* Eb   = ws + WS_EB;
  const char* zb16 = ws + WS_ZB16;

  char* bufA    = lds + w * 16384;           // wave-private chunk buffers
  char* bufB    = bufA + 8192;
  float* eNormW = (float*)(lds + 65536 + w * 1024);  // wave's 256 norms
  float2* cand  = (float2*)(lds + 69632);    // [4 waves][64 rows]

  // staging source offsets for one 16-code chunk (XOR granule swizzle baked in):
  // LDS[q][s] = E[q][s ^ (q&7)], q = code-in-chunk, s/granule of 16 B.
  int srcOff[8];
  #pragma unroll
  for (int i = 0; i < 8; ++i) {
    const int j = i * 64 + l;                // LDS granule 0..511
    const int q = j >> 5;                    // code-in-chunk 0..15
    const int g = (j & 31) ^ (q & 7);        // source granule (un-swizzle)
    srcOff[i] = q * 512 + g * 16;
  }
  const char* EbW = Eb + (size_t)w * 131072; // wave's 256 codes (128 KB)

  // stage chunk 0 + wave's eNorm slice (9 loads outstanding)
  #pragma unroll
  for (int i = 0; i < 8; ++i)
    load16(EbW + srcOff[i], bufA + i * 1024 + l * 16);
  load16((const char*)(ws + WS_ENORM) + w * 1024 + l * 16, (char*)eNormW + l * 16);

  // af: 64 rows x K=256, identical in all waves (proven round-6 layout).
  // asm keep-alive on 32-bit words: makes each fragment opaque so the compiler
  // CANNOT rematerialize it from zb16 inside the chunk loop (r11 diagnosis).
  union afu_t { bf16x8 v; unsigned u[4]; } af[4][8];
  const int rb0 = mt * 4;
  #pragma unroll
  for (int rs = 0; rs < 4; ++rs)
    #pragma unroll
    for (int kg = 0; kg < 8; ++kg)
      af[rs][kg].v = *(const bf16x8*)(zb16 + ((size_t)(((rb0 + rs) * 8 + kg) * 64 + l)) * 16);
  #pragma unroll
  for (int rs = 0; rs < 4; ++rs)
    #pragma unroll
    for (int kg = 0; kg < 8; ++kg)
      asm volatile("" : "+v"(af[rs][kg].u[0]), "+v"(af[rs][kg].u[1]),
                        "+v"(af[rs][kg].u[2]), "+v"(af[rs][kg].u[3]));

  float bb[4][4]; int bidx[4][4];
  #pragma unroll
  for (int rs = 0; rs < 4; ++rs)
    #pragma unroll
    for (int i = 0; i < 4; ++i) { bb[rs][i] = 3.4e38f; bidx[rs][i] = 0; }

  char* bcur = bufA;
  char* bnxt = bufB;
  for (int ch = 0; ch < 16; ++ch) {
    if (ch < 15) {                           // stage next chunk into other buf
      const char* src = EbW + (size_t)(ch + 1) * 8192;
      #pragma unroll
      for (int i = 0; i < 8; ++i)
        load16(src + srcOff[i], bnxt + i * 1024 + l * 16);
      // retire everything except the 8 loads just issued (chunk ch ready)
      asm volatile("s_waitcnt vmcnt(8)" ::: "memory");
    } else {
      asm volatile("s_waitcnt vmcnt(0)" ::: "memory");
    }
    __builtin_amdgcn_sched_barrier(0);

    f32x4 acc[4];
    #pragma unroll
    for (int rs = 0; rs < 4; ++rs) acc[rs] = (f32x4){0.f, 0.f, 0.f, 0.f};
    const char* ebase = bcur + lrow * 512;
    #pragma unroll
    for (int kg = 0; kg < 8; ++kg) {
      const bf16x8 bf = *(const bf16x8*)(ebase + (((kg * 4 + lk) ^ (lrow & 7)) * 16));
      acc[0] = __builtin_amdgcn_mfma_f32_16x16x32_bf16(af[0][kg].v, bf, acc[0], 0, 0, 0);
      acc[1] = __builtin_amdgcn_mfma_f32_16x16x32_bf16(af[1][kg].v, bf, acc[1], 0, 0, 0);
      acc[2] = __builtin_amdgcn_mfma_f32_16x16x32_bf16(af[2][kg].v, bf, acc[2], 0, 0, 0);
      acc[3] = __builtin_amdgcn_mfma_f32_16x16x32_bf16(af[3][kg].v, bf, acc[3], 0, 0, 0);
    }
    // fold (codes ascending within wave; strict < keeps first index)
    const int code = w * 256 + ch * 16 + lrow;
    const float eN = eNormW[ch * 16 + lrow];
    #pragma unroll
    for (int rs = 0; rs < 4; ++rs)
      #pragma unroll
      for (int i = 0; i < 4; ++i) {
        const float sc = fmaf(-2.f, acc[rs][i], eN);
        if (sc < bb[rs][i]) { bb[rs][i] = sc; bidx[rs][i] = code; }
      }
    char* tsw = bcur; bcur = bnxt; bnxt = tsw;
  }

  // reduce over 16 code-lanes (lrow bits), then cross-wave via LDS
  #pragma unroll
  for (int rs = 0; rs < 4; ++rs)
    #pragma unroll
    for (int i = 0; i < 4; ++i)
      #pragma unroll
      for (int m = 8; m >= 1; m >>= 1) {
        const float ob = __shfl_xor(bb[rs][i], m);
        const int   oi = __shfl_xor(bidx[rs][i], m);
        if (ob < bb[rs][i] || (ob == bb[rs][i] && oi < bidx[rs][i])) { bb[rs][i] = ob; bidx[rs][i] = oi; }
      }
  if (lrow == 0) {
    #pragma unroll
    for (int rs = 0; rs < 4; ++rs)
      #pragma unroll
      for (int i = 0; i < 4; ++i) {
        float2 c2; c2.x = bb[rs][i]; c2.y = __int_as_float(bidx[rs][i]);
        cand[w * 64 + rs * 16 + lk * 4 + i] = c2;   // row = rs*16+lk*4+i
      }
  }
  __syncthreads();                           // only block-wide sync in the kernel
  if (t < 64) {
    float best = 3.4e38f; int bi = 0x7fffffff;
    #pragma unroll
    for (int wv = 0; wv < 4; ++wv) {
      const float2 c2 = cand[wv * 64 + t];
      const int ci2 = __float_as_int(c2.y);
      if (c2.x < best || (c2.x == best && ci2 < bi)) { best = c2.x; bi = ci2; }
    }
    ((int*)(ws + WS_IDX))[m0 + t] = bi;
    float d = ((const float*)(ws + WS_ZNORM))[m0 + t] + best;
    #pragma unroll
    for (int m = 32; m >= 1; m >>= 1) d += __shfl_xor(d, m);
    if (t == 0) atomicAdd((float*)(ws + WS_LOSS), d);
  }
}

// Gather quant_z (f32 exact) via padded LDS transpose; block 0 writes losses.
__global__ __launch_bounds__(256, 4)
void vq_gather(const float* __restrict__ E, const char* __restrict__ ws,
               float* __restrict__ out) {
  __shared__ float tile[256][33];
  __shared__ int idxS[32];
  const int t = threadIdx.x;
  const int n = blockIdx.x >> 5, hw0 = (blockIdx.x & 31) * 32;
  if (t < 32) idxS[t] = ((const int*)(ws + WS_IDX))[n * 1024 + hw0 + t];
  if (blockIdx.x == 0 && t == 0) {           // argmin dispatch already complete
    const float L = *((const float*)(ws + WS_LOSS)) * (1.0f / 8388608.0f);
    out[8388608] = L;
    out[8388609] = 0.25f * L;
  }
  __syncthreads();

  const int hw = t >> 3, q = t & 7;
  const float4* erow = (const float4*)(E + (size_t)idxS[hw] * CDIM);
  #pragma unroll
  for (int j = 0; j < 8; ++j) {
    const int p = q + j * 8;
    const float4 v = erow[p];
    tile[p * 4 + 0][hw] = v.x;
    tile[p * 4 + 1][hw] = v.y;
    tile[p * 4 + 2][hw] = v.z;
    tile[p * 4 + 3][hw] = v.w;
  }
  __syncthreads();

  float* obase = out + (size_t)n * (CDIM * 1024) + hw0;
  const int hw4 = (t & 7) * 4, c0 = t >> 3;
  #pragma unroll
  for (int j = 0; j < 8; ++j) {
    const int c = c0 + j * 32;
    float4 v;
    v.x = tile[c][hw4 + 0];
    v.y = tile[c][hw4 + 1];
    v.z = tile[c][hw4 + 2];
    v.w = tile[c][hw4 + 3];
    *(float4*)(obase + (size_t)c * 1024 + hw4) = v;
  }
}

extern "C" void kernel_launch(void* const* d_in, const int* in_sizes, int n_in,
                              void* d_out, int out_size, void* d_ws, size_t ws_size,
                              hipStream_t stream) {
  const float* z = (const float*)d_in[0];
  const float* E = (const float*)d_in[1];
  float* out = (float*)d_out;
  char*  ws  = (char*)d_ws;

  static const int kLdsArg = 71680;          // 4x(16K buf) + 4x1K eNorm + 2K cand
  (void)hipFuncSetAttribute((const void*)vq_argmin,
                            hipFuncAttributeMaxDynamicSharedMemorySize, kLdsArg);

  vq_pack  <<<768, 256, 0, stream>>>(z, E, ws);
  vq_argmin<<<512, 256, kLdsArg, stream>>>(ws);
  vq_gather<<<1024, 256, 0, stream>>>(E, ws, out);
}